// Round 1
// baseline (1011.583 us; speedup 1.0000x reference)
//
#include <hip/hip_runtime.h>
#include <cfloat>

#define B_    1024
#define T_    4
#define DIN   768
#define KD    3072      // T_*DIN, contracted dim of encoder
#define DSAE  8192
#define TOPK  32

static constexpr size_t XHAT_OFF = 1;
static constexpr size_t Z_OFF    = 1 + (size_t)B_ * T_ * DIN;   // 3145729

// ---------------------------------------------------------------- K0: zero fp64 loss accumulator
__global__ void zero_acc(double* acc) { if (threadIdx.x == 0) *acc = 0.0; }

// ---------------------------------------------------------------- K1: fp32 tiled GEMM  pre = X*W + b_enc
// X: (1024 x 3072) row-major, W: (3072 x 8192) row-major, pre: (1024 x 8192) row-major (z region of d_out)
__global__ __launch_bounds__(256) void encode_gemm(const float* __restrict__ x,
                                                   const float* __restrict__ W,
                                                   const float* __restrict__ benc,
                                                   float* __restrict__ pre)
{
    __shared__ float As[16][128];   // [k][m] (A transposed into LDS)
    __shared__ float Ws[16][128];   // [k][n]
    const int tid = threadIdx.x;
    const int tx = tid & 15, ty = tid >> 4;          // 16x16 thread grid, each does 8x8
    const int m0 = blockIdx.y * 128, n0 = blockIdx.x * 128;

    float acc[8][8];
    #pragma unroll
    for (int i = 0; i < 8; i++)
        #pragma unroll
        for (int j = 0; j < 8; j++) acc[i][j] = 0.f;

    const int lr = tid >> 2, lc = (tid & 3) << 2;    // A-tile loader: 4 lanes/row, float4
    const int wr = tid >> 5, wc = (tid & 31) << 2;   // W-tile loader: 32 lanes/row, float4

    for (int k0 = 0; k0 < KD; k0 += 16) {
        #pragma unroll
        for (int p = 0; p < 2; p++) {
            int m = lr + p * 64;
            float4 v = *(const float4*)(x + (size_t)(m0 + m) * KD + k0 + lc);
            As[lc + 0][m] = v.x; As[lc + 1][m] = v.y; As[lc + 2][m] = v.z; As[lc + 3][m] = v.w;
        }
        #pragma unroll
        for (int p = 0; p < 2; p++) {
            int kk = wr + p * 8;
            *(float4*)&Ws[kk][wc] = *(const float4*)(W + (size_t)(k0 + kk) * DSAE + n0 + wc);
        }
        __syncthreads();
        #pragma unroll
        for (int kk = 0; kk < 16; kk++) {
            float a[8], b[8];
            *(float4*)&a[0] = *(const float4*)&As[kk][ty * 8];
            *(float4*)&a[4] = *(const float4*)&As[kk][ty * 8 + 4];
            *(float4*)&b[0] = *(const float4*)&Ws[kk][tx * 8];
            *(float4*)&b[4] = *(const float4*)&Ws[kk][tx * 8 + 4];
            #pragma unroll
            for (int i = 0; i < 8; i++)
                #pragma unroll
                for (int j = 0; j < 8; j++)
                    acc[i][j] = fmaf(a[i], b[j], acc[i][j]);
        }
        __syncthreads();
    }
    #pragma unroll
    for (int i = 0; i < 8; i++) {
        size_t m = (size_t)m0 + ty * 8 + i;
        #pragma unroll
        for (int j = 0; j < 8; j++) {
            int n = n0 + tx * 8 + j;
            pre[m * DSAE + n] = acc[i][j] + benc[n];
        }
    }
}

// ---------------------------------------------------------------- K2: exact top-32 selection (one block per row)
// Reads the pre row (from the z region), selects top-32 with fp64 arbitration at the boundary,
// overwrites the row in-place with sparse z, and emits compact (idx, relu(val)) winner lists.
__global__ __launch_bounds__(256) void select_topk(float* __restrict__ zout,
                                                   const float* __restrict__ x,
                                                   const float* __restrict__ W,
                                                   int* __restrict__ widx_g,
                                                   float* __restrict__ wval_g)
{
    const int b   = blockIdx.x;
    const int tid = threadIdx.x;

    __shared__ float vals[DSAE];            // 32 KB
    __shared__ unsigned char flag[DSAE];    // 8 KB
    __shared__ float rv[256];  __shared__ int ri[256];
    __shared__ double dred[256];
    __shared__ float topv[TOPK]; __shared__ int topi[TOPK];
    __shared__ int wix[64]; __shared__ double wdv[64]; __shared__ unsigned char wsel[64];
    __shared__ int wcnt, nabove, outc;

    float* zrow = zout + (size_t)b * DSAE;
    #pragma unroll
    for (int p = 0; p < DSAE / 256; p++) vals[tid + p * 256] = zrow[tid + p * 256];
    __syncthreads();

    // 32 block-wide argmax passes (tie-break: lower index) on the fp32 approximation
    for (int pass = 0; pass < TOPK; pass++) {
        float bv = -FLT_MAX; int bi = 0x7fffffff;
        #pragma unroll
        for (int p = 0; p < DSAE / 256; p++) {
            int i = tid + p * 256;
            float v = vals[i];
            if (v > bv) { bv = v; bi = i; }
        }
        rv[tid] = bv; ri[tid] = bi; __syncthreads();
        for (int s = 128; s > 0; s >>= 1) {
            if (tid < s) {
                if (rv[tid + s] > rv[tid] || (rv[tid + s] == rv[tid] && ri[tid + s] < ri[tid])) {
                    rv[tid] = rv[tid + s]; ri[tid] = ri[tid + s];
                }
            }
            __syncthreads();
        }
        if (tid == 0) { topv[pass] = rv[0]; topi[pass] = ri[0]; vals[ri[0]] = -FLT_MAX; }
        __syncthreads();
    }
    // restore the 32 marked values
    if (tid < TOPK) vals[topi[tid]] = topv[tid];
    if (tid == 0) { wcnt = 0; nabove = 0; outc = 0; }
    __syncthreads();

    const float v32 = topv[TOPK - 1];
    const float mgn = 1e-3f;   // ~250 sigma of fp32 GEMM error; order-stat spacing ~0.021

    // classify: definitely-in (> v32+mgn), boundary window [v32-mgn, v32+mgn], definitely-out
    for (int p = 0; p < DSAE / 256; p++) {
        int i = tid + p * 256;
        float v = vals[i];
        if (v > v32 + mgn) { atomicAdd(&nabove, 1); }
        else if (v >= v32 - mgn) { int slot = atomicAdd(&wcnt, 1); if (slot < 64) wix[slot] = i; }
    }
    __syncthreads();
    const int nw   = wcnt < 64 ? wcnt : 64;
    const int need = TOPK - nabove;          // >= 1 always (rank-32 atom lives in the window)

    if (nw == need) {
        if (tid < 64) wsel[tid] = (tid < nw) ? 1 : 0;   // all window atoms are in: no arbitration
    } else {
        // fp64-exact re-computation of each window atom's pre-activation (rare: ~5% of rows)
        const float* xr = x + (size_t)b * KD;
        for (int w = 0; w < nw; w++) {
            const int s = wix[w];
            double part = 0.0;
            for (int kk = tid; kk < KD; kk += 256)
                part += (double)xr[kk] * (double)W[(size_t)kk * DSAE + s];
            dred[tid] = part; __syncthreads();
            for (int st = 128; st > 0; st >>= 1) { if (tid < st) dred[tid] += dred[tid + st]; __syncthreads(); }
            if (tid == 0) wdv[w] = dred[0];
            __syncthreads();
        }
        if (tid < 64) {
            unsigned char sel = 0;
            if (tid < nw) {
                int rank = 0;
                double mv = wdv[tid]; int mi = wix[tid];
                for (int w2 = 0; w2 < nw; w2++)
                    if (wdv[w2] > mv || (wdv[w2] == mv && wix[w2] < mi)) rank++;
                sel = (rank < need) ? 1 : 0;
            }
            wsel[tid] = sel;
        }
    }
    __syncthreads();

    // build winner flags
    for (int p = 0; p < DSAE / 256; p++) flag[tid + p * 256] = 0;
    __syncthreads();
    for (int p = 0; p < DSAE / 256; p++) {
        int i = tid + p * 256;
        if (vals[i] > v32 + mgn) flag[i] = 1;
    }
    if (tid < nw && wsel[tid]) flag[wix[tid]] = 1;
    __syncthreads();

    // write sparse z row in-place + compact winner list for the decoder
    for (int p = 0; p < DSAE / 256; p++) {
        int i = tid + p * 256;
        float v = vals[i];
        float zv = 0.f;
        if (flag[i]) {
            zv = v > 0.f ? v : 0.f;              // relu
            int slot = atomicAdd(&outc, 1);
            if (slot < TOPK) { widx_g[b * TOPK + slot] = i; wval_g[b * TOPK + slot] = zv; }
        }
        zrow[i] = zv;
    }
}

// ---------------------------------------------------------------- K3: sparse decode + fused loss (one block per sample)
__global__ __launch_bounds__(256) void decode_loss(const int* __restrict__ widx_g,
                                                   const float* __restrict__ wval_g,
                                                   const float* __restrict__ Wdec,
                                                   const float* __restrict__ bdec,
                                                   const float* __restrict__ x,
                                                   float* __restrict__ xhat,
                                                   double* __restrict__ acc)
{
    const int b = blockIdx.x, tid = threadIdx.x;
    __shared__ int sidx[TOPK]; __shared__ float sval[TOPK];
    __shared__ double dred[256];
    if (tid < TOPK) { sidx[tid] = widx_g[b * TOPK + tid]; sval[tid] = wval_g[b * TOPK + tid]; }
    __syncthreads();

    float o[KD / 256];                       // 12 outputs per thread, strided for coalescing
    #pragma unroll
    for (int c = 0; c < KD / 256; c++) o[c] = bdec[tid + c * 256];

    for (int j = 0; j < TOPK; j++) {
        float v = sval[j];
        const float* wr = Wdec + (size_t)sidx[j] * KD + tid;
        #pragma unroll
        for (int c = 0; c < KD / 256; c++) o[c] = fmaf(v, wr[c * 256], o[c]);
    }

    double ls = 0.0;
    const float* xr = x + (size_t)b * KD;
    float* xo = xhat + (size_t)b * KD;
    #pragma unroll
    for (int c = 0; c < KD / 256; c++) {
        int e = tid + c * 256;
        float ov = o[c];
        float d  = ov - xr[e];
        ls += (double)d * (double)d;
        xo[e] = ov;
    }
    dred[tid] = ls; __syncthreads();
    for (int s = 128; s > 0; s >>= 1) { if (tid < s) dred[tid] += dred[tid + s]; __syncthreads(); }
    if (tid == 0) atomicAdd(acc, dred[0]);
}

// ---------------------------------------------------------------- K4: finalize loss scalar
__global__ void finalize(const double* __restrict__ acc, float* __restrict__ out)
{
    if (threadIdx.x == 0) out[0] = (float)(*acc / (double)(B_ * T_));
}

// ----------------------------------------------------------------
extern "C" void kernel_launch(void* const* d_in, const int* in_sizes, int n_in,
                              void* d_out, int out_size, void* d_ws, size_t ws_size,
                              hipStream_t stream)
{
    (void)in_sizes; (void)n_in; (void)out_size; (void)ws_size;
    const float* x    = (const float*)d_in[0];
    const float* Wenc = (const float*)d_in[1];
    const float* Wdec = (const float*)d_in[2];
    const float* benc = (const float*)d_in[3];
    const float* bdec = (const float*)d_in[4];
    // d_in[5] = k (always 32, baked in)

    float*  out    = (float*)d_out;
    double* acc    = (double*)d_ws;
    int*    widx_g = (int*)((char*)d_ws + 16);
    float*  wval_g = (float*)((char*)d_ws + 16 + (size_t)B_ * TOPK * 4);

    float* pre  = out + Z_OFF;     // z region doubles as the dense pre buffer (same size/layout)
    float* xhat = out + XHAT_OFF;

    hipLaunchKernelGGL(zero_acc,    dim3(1),                  dim3(1),   0, stream, acc);
    hipLaunchKernelGGL(encode_gemm, dim3(DSAE/128, B_/128),   dim3(256), 0, stream, x, Wenc, benc, pre);
    hipLaunchKernelGGL(select_topk, dim3(B_),                 dim3(256), 0, stream, pre, x, Wenc, widx_g, wval_g);
    hipLaunchKernelGGL(decode_loss, dim3(B_),                 dim3(256), 0, stream, widx_g, wval_g, Wdec, bdec, x, xhat, acc);
    hipLaunchKernelGGL(finalize,    dim3(1),                  dim3(1),   0, stream, acc, out);
}

// Round 2
// 671.604 us; speedup vs baseline: 1.5062x; 1.5062x over previous
//
#include <hip/hip_runtime.h>
#include <cfloat>

#define B_    1024
#define T_    4
#define DIN   768
#define KD    3072      // T_*DIN, contracted dim of encoder
#define DSAE  8192
#define TOPK  32

static constexpr size_t XHAT_OFF = 1;
static constexpr size_t Z_OFF    = 1 + (size_t)B_ * T_ * DIN;   // 3145729

typedef __attribute__((ext_vector_type(8))) short  frag;    // 8 bf16 = 4 VGPRs
typedef __attribute__((ext_vector_type(4))) float  f32x4;   // MFMA C/D

__device__ __forceinline__ unsigned pack2(float a, float b) {
    // bf16(trunc) of a in low half, bf16(trunc) of b in high half
    return (__builtin_bit_cast(unsigned, a) >> 16) | (__builtin_bit_cast(unsigned, b) & 0xFFFF0000u);
}
__device__ __forceinline__ float hi_part(float a) {
    return __builtin_bit_cast(float, __builtin_bit_cast(unsigned, a) & 0xFFFF0000u);
}

// ---------------------------------------------------------------- K0
__global__ void zero_acc(double* acc) { if (threadIdx.x == 0) *acc = 0.0; }

// ---------------------------------------------------------------- K1: bf16x2-split MFMA GEMM  pre = X*W + b_enc
// X: (1024 x 3072) fp32 row-major, W: (3072 x 8192) fp32 row-major -> pre (1024 x 8192) fp32.
// Split fp32 -> hi/lo bf16 during staging; pre = Xhi*Whi + Xhi*Wlo + Xlo*Whi (lo*lo negligible).
#define PK 40           // LDS row pitch in bf16 units (80 B: 16B-aligned b128 frags, conflict-free)
__global__ __launch_bounds__(256, 2) void encode_mfma(const float* __restrict__ x,
                                                      const float* __restrict__ W,
                                                      const float* __restrict__ benc,
                                                      float* __restrict__ pre)
{
    __shared__ short Ahi[128 * PK], Alo[128 * PK];   // [m][k]  10 KB each
    __shared__ short Bhi[128 * PK], Blo[128 * PK];   // [n][k]  (transposed W tile)

    const int tid  = threadIdx.x;
    const int m0   = blockIdx.y * 128, n0 = blockIdx.x * 128;
    // A staging: thread -> (row am, 16 k's starting at ak)
    const int am = tid >> 1, ak = (tid & 1) << 4;
    // B staging: thread -> 4x4 block at (k = bk*4.., n = bn..)
    const int bn = (tid & 31) << 2, bk = tid >> 5;
    // fragment/lane ids
    const int lane = tid & 63, wv = tid >> 6;
    const int wrow = (wv >> 1) * 64, wcol = (wv & 1) * 64;
    const int lm = lane & 15, q = lane >> 4;

    f32x4 acc[4][4];
    #pragma unroll
    for (int i = 0; i < 4; i++)
        #pragma unroll
        for (int j = 0; j < 4; j++) acc[i][j] = (f32x4){0.f, 0.f, 0.f, 0.f};

    const float* pA0 = x + (size_t)(m0 + am) * KD + ak;
    const float* pB0 = W + (size_t)bk * 4 * DSAE + n0 + bn;

    for (int k0 = 0; k0 < KD; k0 += 32) {
        // ---- stage A (128 x 32): 16 consecutive k per thread, natural layout
        {
            const float* pA = pA0 + k0;
            float f[16];
            *(float4*)&f[0]  = *(const float4*)(pA);
            *(float4*)&f[4]  = *(const float4*)(pA + 4);
            *(float4*)&f[8]  = *(const float4*)(pA + 8);
            *(float4*)&f[12] = *(const float4*)(pA + 12);
            unsigned hw[8], lw[8];
            #pragma unroll
            for (int j = 0; j < 8; j++) {
                float a = f[2*j], b = f[2*j+1];
                float ha = hi_part(a), hb = hi_part(b);
                hw[j] = pack2(ha, hb);
                lw[j] = pack2(a - ha, b - hb);
            }
            short* dh = &Ahi[am * PK + ak];
            short* dl = &Alo[am * PK + ak];
            *(int4*)dh       = *(int4*)&hw[0];
            *(int4*)(dh + 8) = *(int4*)&hw[4];
            *(int4*)dl       = *(int4*)&lw[0];
            *(int4*)(dl + 8) = *(int4*)&lw[4];
        }
        // ---- stage B (32k x 128n) transposed into [n][k] via 4x4 register blocks
        {
            const float* pB = pB0 + (size_t)k0 * DSAE;
            float4 w0 = *(const float4*)(pB);
            float4 w1 = *(const float4*)(pB + DSAE);
            float4 w2 = *(const float4*)(pB + 2 * DSAE);
            float4 w3 = *(const float4*)(pB + 3 * DSAE);
            float fr[4][4] = {{w0.x,w0.y,w0.z,w0.w},{w1.x,w1.y,w1.z,w1.w},
                              {w2.x,w2.y,w2.z,w2.w},{w3.x,w3.y,w3.z,w3.w}};
            #pragma unroll
            for (int c = 0; c < 4; c++) {
                float h0 = hi_part(fr[0][c]), h1 = hi_part(fr[1][c]);
                float h2 = hi_part(fr[2][c]), h3 = hi_part(fr[3][c]);
                unsigned hh[2] = { pack2(h0, h1), pack2(h2, h3) };
                unsigned ll[2] = { pack2(fr[0][c]-h0, fr[1][c]-h1), pack2(fr[2][c]-h2, fr[3][c]-h3) };
                *(int2*)&Bhi[(bn + c) * PK + bk * 4] = *(int2*)&hh[0];
                *(int2*)&Blo[(bn + c) * PK + bk * 4] = *(int2*)&ll[0];
            }
        }
        __syncthreads();

        // ---- fragments + 3-product MFMA
        frag ah[4], al[4], bh[4], bl[4];
        #pragma unroll
        for (int t4 = 0; t4 < 4; t4++) {
            int r = (wrow + t4 * 16 + lm) * PK + q * 8;
            ah[t4] = *(const frag*)&Ahi[r];
            al[t4] = *(const frag*)&Alo[r];
            int cIdx = (wcol + t4 * 16 + lm) * PK + q * 8;
            bh[t4] = *(const frag*)&Bhi[cIdx];
            bl[t4] = *(const frag*)&Blo[cIdx];
        }
        #pragma unroll
        for (int mt = 0; mt < 4; mt++)
            #pragma unroll
            for (int nt = 0; nt < 4; nt++) {
                acc[mt][nt] = __builtin_amdgcn_mfma_f32_16x16x32_bf16(ah[mt], bh[nt], acc[mt][nt], 0, 0, 0);
                acc[mt][nt] = __builtin_amdgcn_mfma_f32_16x16x32_bf16(ah[mt], bl[nt], acc[mt][nt], 0, 0, 0);
                acc[mt][nt] = __builtin_amdgcn_mfma_f32_16x16x32_bf16(al[mt], bh[nt], acc[mt][nt], 0, 0, 0);
            }
        __syncthreads();
    }

    // ---- epilogue: C/D layout col=lane&15, row=q*4+reg
    #pragma unroll
    for (int mt = 0; mt < 4; mt++)
        #pragma unroll
        for (int nt = 0; nt < 4; nt++) {
            int col = n0 + wcol + nt * 16 + lm;
            float bv = benc[col];
            #pragma unroll
            for (int r = 0; r < 4; r++) {
                int row = m0 + wrow + mt * 16 + q * 4 + r;
                pre[(size_t)row * DSAE + col] = acc[mt][nt][r] + bv;
            }
        }
}

// ---------------------------------------------------------------- K2: exact top-32 selection (one block per row)
__global__ __launch_bounds__(256) void select_topk(float* __restrict__ zout,
                                                   const float* __restrict__ x,
                                                   const float* __restrict__ W,
                                                   int* __restrict__ widx_g,
                                                   float* __restrict__ wval_g)
{
    const int b   = blockIdx.x;
    const int tid = threadIdx.x;

    __shared__ float vals[DSAE];            // 32 KB
    __shared__ unsigned char flag[DSAE];    // 8 KB
    __shared__ float rv[256];  __shared__ int ri[256];
    __shared__ double dred[256];
    __shared__ float topv[TOPK]; __shared__ int topi[TOPK];
    __shared__ int wix[64]; __shared__ double wdv[64]; __shared__ unsigned char wsel[64];
    __shared__ int wcnt, nabove, outc;

    float* zrow = zout + (size_t)b * DSAE;
    #pragma unroll
    for (int p = 0; p < DSAE / 256; p++) vals[tid + p * 256] = zrow[tid + p * 256];
    __syncthreads();

    for (int pass = 0; pass < TOPK; pass++) {
        float bv = -FLT_MAX; int bi = 0x7fffffff;
        #pragma unroll
        for (int p = 0; p < DSAE / 256; p++) {
            int i = tid + p * 256;
            float v = vals[i];
            if (v > bv) { bv = v; bi = i; }
        }
        rv[tid] = bv; ri[tid] = bi; __syncthreads();
        for (int s = 128; s > 0; s >>= 1) {
            if (tid < s) {
                if (rv[tid + s] > rv[tid] || (rv[tid + s] == rv[tid] && ri[tid + s] < ri[tid])) {
                    rv[tid] = rv[tid + s]; ri[tid] = ri[tid + s];
                }
            }
            __syncthreads();
        }
        if (tid == 0) { topv[pass] = rv[0]; topi[pass] = ri[0]; vals[ri[0]] = -FLT_MAX; }
        __syncthreads();
    }
    if (tid < TOPK) vals[topi[tid]] = topv[tid];
    if (tid == 0) { wcnt = 0; nabove = 0; outc = 0; }
    __syncthreads();

    const float v32 = topv[TOPK - 1];
    const float mgn = 2e-3f;   // ~60 sigma of bf16x2 GEMM error; order-stat spacing ~0.021

    for (int p = 0; p < DSAE / 256; p++) {
        int i = tid + p * 256;
        float v = vals[i];
        if (v > v32 + mgn) { atomicAdd(&nabove, 1); }
        else if (v >= v32 - mgn) { int slot = atomicAdd(&wcnt, 1); if (slot < 64) wix[slot] = i; }
    }
    __syncthreads();
    const int nw   = wcnt < 64 ? wcnt : 64;
    const int need = TOPK - nabove;

    if (nw == need) {
        if (tid < 64) wsel[tid] = (tid < nw) ? 1 : 0;
    } else {
        // fp64-exact re-computation of window atoms (rare)
        const float* xr = x + (size_t)b * KD;
        for (int w = 0; w < nw; w++) {
            const int s = wix[w];
            double part = 0.0;
            for (int kk = tid; kk < KD; kk += 256)
                part += (double)xr[kk] * (double)W[(size_t)kk * DSAE + s];
            dred[tid] = part; __syncthreads();
            for (int st = 128; st > 0; st >>= 1) { if (tid < st) dred[tid] += dred[tid + st]; __syncthreads(); }
            if (tid == 0) wdv[w] = dred[0];
            __syncthreads();
        }
        if (tid < 64) {
            unsigned char sel = 0;
            if (tid < nw) {
                int rank = 0;
                double mv = wdv[tid]; int mi = wix[tid];
                for (int w2 = 0; w2 < nw; w2++)
                    if (wdv[w2] > mv || (wdv[w2] == mv && wix[w2] < mi)) rank++;
                sel = (rank < need) ? 1 : 0;
            }
            wsel[tid] = sel;
        }
    }
    __syncthreads();

    for (int p = 0; p < DSAE / 256; p++) flag[tid + p * 256] = 0;
    __syncthreads();
    for (int p = 0; p < DSAE / 256; p++) {
        int i = tid + p * 256;
        if (vals[i] > v32 + mgn) flag[i] = 1;
    }
    if (tid < nw && wsel[tid]) flag[wix[tid]] = 1;
    __syncthreads();

    for (int p = 0; p < DSAE / 256; p++) {
        int i = tid + p * 256;
        float v = vals[i];
        float zv = 0.f;
        if (flag[i]) {
            zv = v > 0.f ? v : 0.f;
            int slot = atomicAdd(&outc, 1);
            if (slot < TOPK) { widx_g[b * TOPK + slot] = i; wval_g[b * TOPK + slot] = zv; }
        }
        zrow[i] = zv;
    }
}

// ---------------------------------------------------------------- K3: sparse decode + fused loss (one block per sample)
__global__ __launch_bounds__(256) void decode_loss(const int* __restrict__ widx_g,
                                                   const float* __restrict__ wval_g,
                                                   const float* __restrict__ Wdec,
                                                   const float* __restrict__ bdec,
                                                   const float* __restrict__ x,
                                                   float* __restrict__ xhat,
                                                   double* __restrict__ acc)
{
    const int b = blockIdx.x, tid = threadIdx.x;
    __shared__ int sidx[TOPK]; __shared__ float sval[TOPK];
    __shared__ double dred[256];
    if (tid < TOPK) { sidx[tid] = widx_g[b * TOPK + tid]; sval[tid] = wval_g[b * TOPK + tid]; }
    __syncthreads();

    float o[KD / 256];
    #pragma unroll
    for (int c = 0; c < KD / 256; c++) o[c] = bdec[tid + c * 256];

    for (int j = 0; j < TOPK; j++) {
        float v = sval[j];
        const float* wr = Wdec + (size_t)sidx[j] * KD + tid;
        #pragma unroll
        for (int c = 0; c < KD / 256; c++) o[c] = fmaf(v, wr[c * 256], o[c]);
    }

    double ls = 0.0;
    const float* xr = x + (size_t)b * KD;
    float* xo = xhat + (size_t)b * KD;
    #pragma unroll
    for (int c = 0; c < KD / 256; c++) {
        int e = tid + c * 256;
        float ov = o[c];
        float d  = ov - xr[e];
        ls += (double)d * (double)d;
        xo[e] = ov;
    }
    dred[tid] = ls; __syncthreads();
    for (int s = 128; s > 0; s >>= 1) { if (tid < s) dred[tid] += dred[tid + s]; __syncthreads(); }
    if (tid == 0) atomicAdd(acc, dred[0]);
}

// ---------------------------------------------------------------- K4: finalize
__global__ void finalize(const double* __restrict__ acc, float* __restrict__ out)
{
    if (threadIdx.x == 0) out[0] = (float)(*acc / (double)(B_ * T_));
}

// ----------------------------------------------------------------
extern "C" void kernel_launch(void* const* d_in, const int* in_sizes, int n_in,
                              void* d_out, int out_size, void* d_ws, size_t ws_size,
                              hipStream_t stream)
{
    (void)in_sizes; (void)n_in; (void)out_size; (void)ws_size;
    const float* x    = (const float*)d_in[0];
    const float* Wenc = (const float*)d_in[1];
    const float* Wdec = (const float*)d_in[2];
    const float* benc = (const float*)d_in[3];
    const float* bdec = (const float*)d_in[4];

    float*  out    = (float*)d_out;
    double* acc    = (double*)d_ws;
    int*    widx_g = (int*)((char*)d_ws + 16);
    float*  wval_g = (float*)((char*)d_ws + 16 + (size_t)B_ * TOPK * 4);

    float* pre  = out + Z_OFF;     // z region doubles as the dense pre buffer
    float* xhat = out + XHAT_OFF;

    hipLaunchKernelGGL(zero_acc,    dim3(1),                dim3(1),   0, stream, acc);
    hipLaunchKernelGGL(encode_mfma, dim3(DSAE/128, B_/128), dim3(256), 0, stream, x, Wenc, benc, pre);
    hipLaunchKernelGGL(select_topk, dim3(B_),               dim3(256), 0, stream, pre, x, Wenc, widx_g, wval_g);
    hipLaunchKernelGGL(decode_loss, dim3(B_),               dim3(256), 0, stream, widx_g, wval_g, Wdec, bdec, x, xhat, acc);
    hipLaunchKernelGGL(finalize,    dim3(1),                dim3(1),   0, stream, acc, out);
}